// Round 11
// baseline (203.280 us; speedup 1.0000x reference)
//
#include <hip/hip_runtime.h>
#include <cstdint>

#define DECAY 0.99f
#define OMD   0.01f
#define EPSV  1e-5f

constexpr int N_PTS   = 32768;  // B*T
constexpr int D_DIM   = 256;
constexpr int C_CODES = 1024;
constexpr int NKT     = 12;     // rescore K-tiles (3 segment-products x 4)
constexpr int BP      = 512;    // B row pitch: [eh | el]

constexpr int PG = 16;          // ind chunks (R10-proven)
constexpr int PK = 8;           // codes per partial block
constexpr int LCAP = 2048;      // worst-case list = chunk size, exact bound

typedef _Float16 half8  __attribute__((ext_vector_type(8)));
typedef _Float16 half4v __attribute__((ext_vector_type(4)));
typedef float    floatx4 __attribute__((ext_vector_type(4)));

// workspace layout (float offsets) — R11: A16 deleted (on-the-fly conversion)
constexpr size_t WS_ENORM = 0;                        // float[1024]
constexpr size_t WS_FCNT  = 1024;                     // int[1]
constexpr size_t WS_XNORM = 2048;                     // float[32768] -> ends 34816
constexpr size_t WS_PCNT  = 34816;                    // int[16*1024] -> ends 51200
constexpr size_t WS_CAND4 = 51200;                    // float4[32768*8] = 1048576 floats
constexpr size_t WS_FLAGR = WS_CAND4 + 1048576;       // int[32768]
constexpr size_t WS_KEY64 = WS_FLAGR + 32768;         // u64[32768] = 65536 floats (8B aligned)
constexpr size_t WS_PBUF  = WS_KEY64 + 65536;         // P[16][1024][256] = 4194304 floats
constexpr size_t WS_B16   = WS_PBUF + 4194304;        // half[1024*512] = 262144 floats
constexpr size_t WS_TOTAL_FLOATS = WS_B16 + 262144;   // ~21.6 MB

__device__ __forceinline__ void async_copy16(const void* g, void* s) {
    __builtin_amdgcn_global_load_lds(
        (const __attribute__((address_space(1))) unsigned int*)(uintptr_t)g,
        (__attribute__((address_space(3))) unsigned int*)(uintptr_t)s, 16, 0, 0);
}

// ordered-uint transform: unsigned compare of u() == float compare
__device__ __forceinline__ unsigned ord_u32(float v) {
    unsigned s = __float_as_uint(v);
    unsigned m = (unsigned)((int)s >> 31);
    return s ^ (m | 0x80000000u);
}
__device__ __forceinline__ float ord_dec(unsigned t) {
    unsigned s = (t & 0x80000000u) ? (t ^ 0x80000000u) : ~t;
    return __uint_as_float(s);
}

// fp16 low-part split, identical ops to the proven prep path
__device__ __forceinline__ _Float16 lo_h(float f) {
    _Float16 h = (_Float16)f;
    return (_Float16)(f - (float)h);
}

// ---------------------------------------------------------------------------
// FUSED prep: blocks [0,8192) wave-reduce xnorm[n] from X (NO A16 write —
// GEMMs convert on the fly); blocks [8192,8448) split e into [eh|el] + enorm.
__global__ __launch_bounds__(256) void vq_prep(const float* __restrict__ X,
                                               const float* __restrict__ E,
                                               _Float16* __restrict__ B,
                                               float* __restrict__ enorm,
                                               float* __restrict__ xnorm,
                                               int* __restrict__ fcnt) {
    if (blockIdx.x < 8192) {
        int i = blockIdx.x * 256 + threadIdx.x;      // float4 index, N*D/4 total
        int n = i >> 6;
        float4 v = reinterpret_cast<const float4*>(X)[i];
        float s = v.x * v.x + v.y * v.y + v.z * v.z + v.w * v.w;
        int lane = threadIdx.x & 63;
#pragma unroll
        for (int off = 32; off > 0; off >>= 1) s += __shfl_down(s, off, 64);
        if (lane == 0) xnorm[n] = s;
    } else {
        if (blockIdx.x == 8192 && threadIdx.x == 0) *fcnt = 0;
        int i = (blockIdx.x - 8192) * 256 + threadIdx.x;  // float4 index, C*D/4
        int c = i >> 6, kq = (i & 63) * 4;
        float4 v = reinterpret_cast<const float4*>(E)[i];
        _Float16 h0 = (_Float16)v.x, h1 = (_Float16)v.y, h2 = (_Float16)v.z, h3 = (_Float16)v.w;
        _Float16 l0 = lo_h(v.x), l1 = lo_h(v.y), l2 = lo_h(v.z), l3 = lo_h(v.w);
        half4v hi = {h0, h1, h2, h3};
        half4v lo = {l0, l1, l2, l3};
        _Float16* row = B + (size_t)c * BP;
        *reinterpret_cast<half4v*>(row + kq)       = hi;
        *reinterpret_cast<half4v*>(row + 256 + kq) = lo;
        float s = v.x * v.x + v.y * v.y + v.z * v.z + v.w * v.w;
        int lane = threadIdx.x & 63;
#pragma unroll
        for (int off = 32; off > 0; off >>= 1) s += __shfl_down(s, off, 64);
        if (lane == 0) enorm[c] = s;
    }
}

// enorm standalone (fallback path only)
__global__ __launch_bounds__(256) void vq_enorm(const float* __restrict__ E,
                                                float* __restrict__ enorm) {
    int c    = blockIdx.x * 4 + (threadIdx.x >> 6);
    int lane = threadIdx.x & 63;
    float4 v = reinterpret_cast<const float4*>(E)[c * 64 + lane];
    float s  = v.x * v.x + v.y * v.y + v.z * v.z + v.w * v.w;
#pragma unroll
    for (int off = 32; off > 0; off >>= 1) s += __shfl_down(s, off, 64);
    if (lane == 0) enorm[c] = s;
}

// ---------------------------------------------------------------------------
// Pass-1 MFMA GEMM: xh*eh only (K=256), 128 rows x 256 codes per block.
// R11: A-tile reg-staged directly from X with in-register fp16 conversion
// (identical ops to the old prep split -> bit-identical operands); the LDS
// placement As[rr*64 + l*8] with source chunk sq=(l&7)^srow reproduces the
// global_load_lds mapping exactly.  B via async gload (issued first).
// Packed-key top-2 DPP epilogue (R6-proven).
#define TOP2_DPP(CTRL)                                                          \
    {                                                                           \
        unsigned o1 = (unsigned)__builtin_amdgcn_update_dpp((int)k1, (int)k1,   \
                                                            CTRL, 0xF, 0xF, false); \
        unsigned o2 = (unsigned)__builtin_amdgcn_update_dpp((int)k2, (int)k2,   \
                                                            CTRL, 0xF, 0xF, false); \
        unsigned tmn = o1 < k1 ? o1 : k1;                                       \
        k1 = o1 > k1 ? o1 : k1;                                                 \
        k2 = o2 > k2 ? o2 : k2;                                                 \
        k2 = tmn > k2 ? tmn : k2;                                               \
    }

__global__ __launch_bounds__(256, 2) void vq_gemm1(
    const float* __restrict__ X, const _Float16* __restrict__ B,
    const float* __restrict__ enorm, float4* __restrict__ cand4) {
    __shared__ _Float16 As[128 * 64];   // 16 KB [row][k], chunks XOR-swizzled by row&7
    __shared__ _Float16 Bs[256 * 64];   // 32 KB

    const int L  = blockIdx.x;              // 0..1023
    const int ct = (L >> 3) & 3;            // code tile 0..3 (256 codes each)
    const int rt = (L & 7) | ((L >> 5) << 3);   // row tile; same rt -> same XCD
    const int n0  = rt * 128;
    const int cb0 = ct * 256;

    const int tid = threadIdx.x;
    const int w   = tid >> 6;
    const int l   = tid & 63;

    const int srow = l >> 3;
    const int sq   = (l & 7) ^ srow;

    floatx4 acc[4][8] = {};

    for (int kt = 0; kt < 4; ++kt) {        // K=256: hi segments only
        const int k0 = kt * 64;
        __syncthreads();
#pragma unroll
        for (int t = 0; t < 8; ++t) {       // B: 256 rows, async (in flight during cvt)
            int rr = w * 64 + t * 8;
            const _Float16* gb = B + (size_t)(cb0 + rr + srow) * BP + k0 + sq * 8;
            async_copy16(gb, &Bs[rr * 64]);
        }
#pragma unroll
        for (int t = 0; t < 4; ++t) {       // A: 128 rows, reg-staged from X
            int rr = w * 32 + t * 8;
            const float* xr = X + (size_t)(n0 + rr + srow) * D_DIM + k0 + sq * 8;
            float4 xa = *reinterpret_cast<const float4*>(xr);
            float4 xb = *reinterpret_cast<const float4*>(xr + 4);
            half8 hv;
            hv[0] = (_Float16)xa.x; hv[1] = (_Float16)xa.y;
            hv[2] = (_Float16)xa.z; hv[3] = (_Float16)xa.w;
            hv[4] = (_Float16)xb.x; hv[5] = (_Float16)xb.y;
            hv[6] = (_Float16)xb.z; hv[7] = (_Float16)xb.w;
            *reinterpret_cast<half8*>(&As[rr * 64 + l * 8]) = hv;
        }
        __syncthreads();
#pragma unroll
        for (int kk = 0; kk < 2; ++kk) {
            half8 af[4], bf[8];
            int qa = kk * 4 + (l >> 4);
#pragma unroll
            for (int i = 0; i < 4; ++i) {
                int row = (w & 1) * 64 + 16 * i + (l & 15);
                af[i] = *reinterpret_cast<const half8*>(&As[row * 64 + (qa ^ (row & 7)) * 8]);
            }
#pragma unroll
            for (int j = 0; j < 8; ++j) {
                int crow = (w >> 1) * 128 + 16 * j + (l & 15);
                bf[j] = *reinterpret_cast<const half8*>(&Bs[crow * 64 + (qa ^ (crow & 7)) * 8]);
            }
#pragma unroll
            for (int i = 0; i < 4; ++i)
#pragma unroll
                for (int j = 0; j < 8; ++j)
                    acc[i][j] = __builtin_amdgcn_mfma_f32_16x16x32_f16(af[i], bf[j], acc[i][j], 0, 0, 0);
        }
    }

    const int colbase = cb0 + (w >> 1) * 128 + (l & 15);
    float    en[8];
    unsigned idxenc[8];
#pragma unroll
    for (int j = 0; j < 8; ++j) {
        en[j]     = enorm[colbase + 16 * j];
        idxenc[j] = 1023u - (unsigned)(colbase + 16 * j);
    }

#pragma unroll
    for (int i = 0; i < 4; ++i) {
#pragma unroll
        for (int reg = 0; reg < 4; ++reg) {
            unsigned k1 = 0u, k2 = 0u;
#pragma unroll
            for (int j = 0; j < 8; ++j) {
                float v = 2.0f * acc[i][j][reg] - en[j];
                unsigned key = (ord_u32(v) & 0xFFFFFC00u) | idxenc[j];
                unsigned tmn = key < k1 ? key : k1;
                k1 = key > k1 ? key : k1;
                k2 = tmn > k2 ? tmn : k2;
            }
            TOP2_DPP(0xB1)   // quad_perm xor1
            TOP2_DPP(0x4E)   // quad_perm xor2
            TOP2_DPP(0x141)  // row_half_mirror
            TOP2_DPP(0x140)  // row_mirror
            if ((l & 15) == 0) {
                unsigned c1 = 1023u - (k1 & 1023u);
                float v1 = ord_dec(k1 & 0xFFFFFC00u);
                float v2 = ord_dec(k2 & 0xFFFFFC00u);
                int row = n0 + (w & 1) * 64 + 16 * i + (l >> 4) * 4 + reg;
                cand4[(size_t)row * 8 + ct * 2 + (w >> 1)] =
                    make_float4(v1, (float)c1, v2, 0.0f);
            }
        }
    }
}

// ---------------------------------------------------------------------------
// Merge top-2 candidates (8/row) -> provisional argmax; flag+compact
// uncertain rows (zero-init their key64 slot); gather quantize.
__global__ __launch_bounds__(256) void vq_merge3f(
    const float4* __restrict__ cand4, const float* __restrict__ E,
    const float* __restrict__ enorm, const float* __restrict__ xnorm,
    float* __restrict__ quant, float* __restrict__ indout,
    int* __restrict__ flagrows, int* __restrict__ fcnt,
    unsigned long long* __restrict__ keyarr) {
    __shared__ int   rowsel[64];
    __shared__ float emred[256];
    const int tid = threadIdx.x;
    const int n0  = blockIdx.x * 64;

    float em = fmaxf(fmaxf(enorm[tid], enorm[tid + 256]),
                     fmaxf(enorm[tid + 512], enorm[tid + 768]));
    emred[tid] = em;
    __syncthreads();
    for (int st = 128; st > 0; st >>= 1) {
        if (tid < st) emred[tid] = fmaxf(emred[tid], emred[tid + st]);
        __syncthreads();
    }
    const float emax = emred[0];

    if (tid < 64) {
        int r = n0 + tid;
        float b1 = -3.4e38f, b2 = -3.4e38f;
        int   i1 = 0x7fffffff;
#pragma unroll
        for (int t = 0; t < 8; ++t) {
            float4 cv = cand4[(size_t)r * 8 + t];
            int ci = (int)cv.y;
            if (cv.x > b1 || (cv.x == b1 && ci < i1)) { b2 = fmaxf(b1, cv.z); b1 = cv.x; i1 = ci; }
            else b2 = fmaxf(b2, cv.x);
        }
        i1 &= (C_CODES - 1);
        rowsel[tid] = i1;
        indout[r]   = (float)i1;
        float T = 0.004150390625f * sqrtf(xnorm[r] * emax)
                + 0.0001220703125f * emax + 0.5f;
        if (b1 - b2 <= T) {
            int p = atomicAdd(fcnt, 1);
            flagrows[p] = r;
            keyarr[p]   = 0ull;            // init for gemm2's atomicMax
        }
    }
    __syncthreads();

    const float4* E4 = reinterpret_cast<const float4*>(E);
    float4*       Q4 = reinterpret_cast<float4*>(quant);
    const int lane = tid & 63;
#pragma unroll
    for (int it = 0; it < 16; ++it) {
        int r   = (tid >> 6) + 4 * it;
        int idx = rowsel[r];
        Q4[(n0 + r) * 64 + lane] = E4[idx * 64 + lane];
    }
}

// ---------------------------------------------------------------------------
// Sparse rescore GEMM: full 3-split (xh*eh + xh*el + xl*eh), DENSE flagged
// slots x 1024 codes.  A operand converted from X in-register (cvt for
// kt<8, lo_h for kt>=8 — identical ops to the proven split -> bit-identical
// dists).  Winner per slot via exact u64 atomicMax key (R9-proven). NO fences.
__global__ __launch_bounds__(256, 2) void vq_gemm2(
    const float* __restrict__ X, const _Float16* __restrict__ B,
    const float* __restrict__ enorm, const int* __restrict__ flagrows,
    const int* __restrict__ fcnt, unsigned long long* __restrict__ keyarr) {
    const int fc = *fcnt;

    const int L      = blockIdx.x;          // 0..2047 (covers worst case)
    const int within = L >> 3;
    const int ct     = within & 7;
    const int rt     = (L & 7) | ((within >> 3) << 3);
    const int n0     = rt * 128;            // dense slot base
    if (n0 >= fc) return;
    const int cb0    = ct * 128;

    __shared__ _Float16 As[128 * 64];
    __shared__ _Float16 Bs[128 * 64];

    const int tid = threadIdx.x;
    const int w   = tid >> 6;
    const int l   = tid & 63;
    const int srow = l >> 3;
    const int sq   = (l & 7) ^ srow;

    int grow[4];
#pragma unroll
    for (int t = 0; t < 4; ++t) {
        int slot = n0 + w * 32 + t * 8 + srow;
        int r    = (slot < fc) ? flagrows[slot] : 0;
        grow[t]  = r & (N_PTS - 1);
    }

    floatx4 acc[4][4] = {};

    for (int kt = 0; kt < NKT; ++kt) {
        // kt 0-3: xh*eh, 4-7: xh*el, 8-11: xl*eh
        const int kxa = ((kt < 8) ? (kt & 3) : (kt - 8)) * 64;   // X source column
        const int kb  = (kt < 4) ? kt * 64 : (kt < 8 ? 256 + (kt - 4) * 64 : (kt - 8) * 64);
        __syncthreads();
#pragma unroll
        for (int t = 0; t < 4; ++t) {       // B: async (in flight during cvt)
            int rr = w * 32 + t * 8;
            const _Float16* gb = B + (size_t)(cb0 + rr + srow) * BP + kb + sq * 8;
            async_copy16(gb, &Bs[rr * 64]);
        }
#pragma unroll
        for (int t = 0; t < 4; ++t) {       // A: reg-staged from X
            int rr = w * 32 + t * 8;
            const float* xr = X + (size_t)grow[t] * D_DIM + kxa + sq * 8;
            float4 xa = *reinterpret_cast<const float4*>(xr);
            float4 xb = *reinterpret_cast<const float4*>(xr + 4);
            half8 hv;
            if (kt < 8) {
                hv[0] = (_Float16)xa.x; hv[1] = (_Float16)xa.y;
                hv[2] = (_Float16)xa.z; hv[3] = (_Float16)xa.w;
                hv[4] = (_Float16)xb.x; hv[5] = (_Float16)xb.y;
                hv[6] = (_Float16)xb.z; hv[7] = (_Float16)xb.w;
            } else {
                hv[0] = lo_h(xa.x); hv[1] = lo_h(xa.y);
                hv[2] = lo_h(xa.z); hv[3] = lo_h(xa.w);
                hv[4] = lo_h(xb.x); hv[5] = lo_h(xb.y);
                hv[6] = lo_h(xb.z); hv[7] = lo_h(xb.w);
            }
            *reinterpret_cast<half8*>(&As[rr * 64 + l * 8]) = hv;
        }
        __syncthreads();
#pragma unroll
        for (int kk = 0; kk < 2; ++kk) {
            half8 af[4], bf[4];
            int qa = kk * 4 + (l >> 4);
#pragma unroll
            for (int i = 0; i < 4; ++i) {
                int row  = (w & 1) * 64 + 16 * i + (l & 15);
                af[i] = *reinterpret_cast<const half8*>(&As[row * 64 + (qa ^ (row & 7)) * 8]);
                int crow = (w >> 1) * 64 + 16 * i + (l & 15);
                bf[i] = *reinterpret_cast<const half8*>(&Bs[crow * 64 + (qa ^ (crow & 7)) * 8]);
            }
#pragma unroll
            for (int i = 0; i < 4; ++i)
#pragma unroll
                for (int j = 0; j < 4; ++j)
                    acc[i][j] = __builtin_amdgcn_mfma_f32_16x16x32_f16(af[i], bf[j], acc[i][j], 0, 0, 0);
        }
    }

    const int colbase = cb0 + (w >> 1) * 64 + (l & 15);
    float en[4];
#pragma unroll
    for (int j = 0; j < 4; ++j) en[j] = enorm[colbase + 16 * j];

#pragma unroll
    for (int i = 0; i < 4; ++i) {
#pragma unroll
        for (int reg = 0; reg < 4; ++reg) {
            float bv = -3.4e38f;
            int   bi = 0x7fffffff;
#pragma unroll
            for (int j = 0; j < 4; ++j) {
                float v = 2.0f * acc[i][j][reg] - en[j];
                int   c = colbase + 16 * j;
                if (v > bv || (v == bv && c < bi)) { bv = v; bi = c; }
            }
#pragma unroll
            for (int s = 1; s < 16; s <<= 1) {
                float ov = __shfl_xor(bv, s, 64);
                int   oi = __shfl_xor(bi, s, 64);
                if (ov > bv || (ov == bv && oi < bi)) { bv = ov; bi = oi; }
            }
            if ((l & 15) == 0) {
                int slot = n0 + (w & 1) * 64 + 16 * i + (l >> 4) * 4 + reg;
                unsigned long long key =
                    ((unsigned long long)ord_u32(bv) << 10) | (1023u - (unsigned)bi);
                atomicMax(&keyarr[slot], key);
            }
        }
    }
}

// ---------------------------------------------------------------------------
// Patch: decode per-slot winner key; overwrite ind + quantize rows.
__global__ __launch_bounds__(256) void vq_patch(
    const unsigned long long* __restrict__ keyarr, const int* __restrict__ flagrows,
    const int* __restrict__ fcnt, const float* __restrict__ E,
    float* __restrict__ quant, float* __restrict__ indout) {
    int fc = *fcnt;
    if (fc > N_PTS) fc = N_PTS;
    const int s0 = blockIdx.x * 64;
    if (s0 >= fc) return;

    __shared__ int rowsel[64];
    __shared__ int rowid[64];
    const int tid = threadIdx.x;
    if (tid < 64) {
        int s = s0 + tid;
        if (s < fc) {
            unsigned long long k = keyarr[s];
            int c = (int)(1023u - (unsigned)(k & 1023u)) & (C_CODES - 1);
            int r = flagrows[s] & (N_PTS - 1);
            rowsel[tid] = c;
            rowid[tid]  = r;
            indout[r]   = (float)c;
        } else {
            rowsel[tid] = -1;
            rowid[tid]  = 0;
        }
    }
    __syncthreads();

    const float4* E4 = reinterpret_cast<const float4*>(E);
    float4*       Q4 = reinterpret_cast<float4*>(quant);
    const int lane = tid & 63;
#pragma unroll
    for (int it = 0; it < 16; ++it) {
        int rs  = (tid >> 6) + 4 * it;
        int idx = rowsel[rs];
        if (idx >= 0) Q4[(size_t)rowid[rs] * 64 + lane] = E4[idx * 64 + lane];
    }
}

// ---------------------------------------------------------------------------
// Partial esum: block (cg, g) scans ind chunk g (2048 entries) for its PK=8
// codes, gathers matching X rows with 8-deep ILP, writes P[g][code][d] +
// counts.  (R10-proven, PG=16.)
__global__ __launch_bounds__(256) void vq_part(
    const float* __restrict__ X, const float* __restrict__ indf,
    float* __restrict__ P, int* __restrict__ pcnt) {
    __shared__ int list[LCAP];
    __shared__ int cnt[PK];
    __shared__ int lcnt;
    const int cg = blockIdx.x;   // 0..127 code group
    const int g  = blockIdx.y;   // 0..15 ind chunk
    const int t  = threadIdx.x;
    if (t == 0) lcnt = 0;
    if (t < PK) cnt[t] = 0;
    __syncthreads();

    const float4* I4 = reinterpret_cast<const float4*>(indf);
    float4 v[2];
#pragma unroll
    for (int j = 0; j < 2; ++j)            // 2 independent loads, one latency round
        v[j] = I4[g * 512 + j * 256 + t];

#pragma unroll
    for (int j = 0; j < 2; ++j) {
        int base = (g * 512 + j * 256 + t) * 4;
        int k0 = (int)v[j].x, k1 = (int)v[j].y, k2 = (int)v[j].z, k3 = (int)v[j].w;
        if ((k0 >> 3) == cg) { int p = atomicAdd(&lcnt, 1); atomicAdd(&cnt[k0 & 7], 1); if (p < LCAP) list[p] = ((base + 0) << 3) | (k0 & 7); }
        if ((k1 >> 3) == cg) { int p = atomicAdd(&lcnt, 1); atomicAdd(&cnt[k1 & 7], 1); if (p < LCAP) list[p] = ((base + 1) << 3) | (k1 & 7); }
        if ((k2 >> 3) == cg) { int p = atomicAdd(&lcnt, 1); atomicAdd(&cnt[k2 & 7], 1); if (p < LCAP) list[p] = ((base + 2) << 3) | (k2 & 7); }
        if ((k3 >> 3) == cg) { int p = atomicAdd(&lcnt, 1); atomicAdd(&cnt[k3 & 7], 1); if (p < LCAP) list[p] = ((base + 3) << 3) | (k3 & 7); }
    }
    __syncthreads();

    int m = lcnt; if (m > LCAP) m = LCAP;
    float acc[PK] = {0, 0, 0, 0, 0, 0, 0, 0};
    int r = 0;
    for (; r + 8 <= m; r += 8) {           // 8 coalesced row loads in flight
        int e[8];
        float val[8];
#pragma unroll
        for (int q = 0; q < 8; ++q) e[q] = list[r + q];
#pragma unroll
        for (int q = 0; q < 8; ++q) val[q] = X[(size_t)(e[q] >> 3) * D_DIM + t];
#pragma unroll
        for (int q = 0; q < 8; ++q) {
            int k = e[q] & 7;
#pragma unroll
            for (int kk = 0; kk < PK; ++kk) acc[kk] += (k == kk) ? val[q] : 0.0f;
        }
    }
    for (; r < m; ++r) {
        int e = list[r];
        float val = X[(size_t)(e >> 3) * D_DIM + t];
        int k = e & 7;
#pragma unroll
        for (int kk = 0; kk < PK; ++kk) acc[kk] += (k == kk) ? val : 0.0f;
    }

#pragma unroll
    for (int kk = 0; kk < PK; ++kk)
        P[((size_t)g * C_CODES + cg * PK + kk) * D_DIM + t] = acc[kk];
    if (t < PK) pcnt[g * C_CODES + cg * PK + t] = cnt[t];
}

// ---------------------------------------------------------------------------
// Combine partials + fused EMA/laplace epilogue + FUSED cs_sum reduction.
__global__ __launch_bounds__(256) void vq_comb(
    const float* __restrict__ P, const int* __restrict__ pcnt,
    const float* __restrict__ ea, const float* __restrict__ cs_in,
    float* __restrict__ emb_norm, float* __restrict__ cs_out) {
    __shared__ float red[256];
    const int c = blockIdx.x;
    const int t = threadIdx.x;
    red[t] = cs_in[t] + cs_in[t + 256] + cs_in[t + 512] + cs_in[t + 768];
    __syncthreads();
    for (int st = 128; st > 0; st >>= 1) {
        if (t < st) red[t] += red[t + st];
        __syncthreads();
    }
    const float cssum = red[0];

    float s = 0.0f;
#pragma unroll
    for (int g = 0; g < PG; ++g)
        s += P[((size_t)g * C_CODES + c) * D_DIM + t];
    int total = 0;
#pragma unroll
    for (int g = 0; g < PG; ++g) total += pcnt[g * C_CODES + c];
    float cs    = DECAY * cs_in[c] + OMD * (float)total;
    float ntot  = DECAY * cssum + OMD * (float)N_PTS;   // sum(cs_new) closed form
    float denom = (cs + EPSV) / (ntot + (float)C_CODES * EPSV) * ntot;
    emb_norm[(size_t)c * D_DIM + t] =
        (DECAY * ea[(size_t)c * D_DIM + t] + OMD * s) / denom;
    if (t == 0) cs_out[c] = cs;
}

// ---------------------------------------------------------------------------
// FALLBACK (R1-proven, only if ws too small): fp32 VALU GEMM + atomic epilogue.
__global__ __launch_bounds__(256) void vq_main_fb(
    const float* __restrict__ X, const float* __restrict__ E,
    const float* __restrict__ enorm,
    float* __restrict__ quant, float* __restrict__ indout,
    float* __restrict__ counts, float* __restrict__ esum) {
    constexpr int BN = 64, BC = 64, BK = 32, PADR = 68;
    __shared__ float As[BK * PADR];
    __shared__ float Bs[BK * PADR];
    __shared__ float redv[BN * 16];
    __shared__ int   redi[BN * 16];
    __shared__ int   rowsel[BN];

    const int tid = threadIdx.x;
    const int n0  = blockIdx.x * BN;
    const int tr  = tid >> 4;
    const int tc  = tid & 15;
    const int sr  = tid >> 2;
    const int sk  = tid & 3;

    const float4* X4 = reinterpret_cast<const float4*>(X);
    const float4* E4 = reinterpret_cast<const float4*>(E);

    float best[4];
    int   bidx[4];
#pragma unroll
    for (int i = 0; i < 4; i++) { best[i] = -3.4e38f; bidx[i] = 0; }

    for (int c0 = 0; c0 < C_CODES; c0 += BC) {
        float acc[4][4] = {};
        for (int k0 = 0; k0 < D_DIM; k0 += BK) {
            __syncthreads();
#pragma unroll
            for (int it = 0; it < 2; ++it) {
                int   k4 = sk + 4 * it;
                float4 av = X4[(n0 + sr) * 64 + (k0 >> 2) + k4];
                float4 bv = E4[(c0 + sr) * 64 + (k0 >> 2) + k4];
                int kk = k4 * 4;
                As[(kk + 0) * PADR + sr] = av.x;
                As[(kk + 1) * PADR + sr] = av.y;
                As[(kk + 2) * PADR + sr] = av.z;
                As[(kk + 3) * PADR + sr] = av.w;
                Bs[(kk + 0) * PADR + sr] = bv.x;
                Bs[(kk + 1) * PADR + sr] = bv.y;
                Bs[(kk + 2) * PADR + sr] = bv.z;
                Bs[(kk + 3) * PADR + sr] = bv.w;
            }
            __syncthreads();
#pragma unroll
            for (int k = 0; k < BK; ++k) {
                float4 a = *reinterpret_cast<const float4*>(&As[k * PADR + 4 * tr]);
                float4 b = *reinterpret_cast<const float4*>(&Bs[k * PADR + 4 * tc]);
                acc[0][0] += a.x * b.x; acc[0][1] += a.x * b.y;
                acc[0][2] += a.x * b.z; acc[0][3] += a.x * b.w;
                acc[1][0] += a.y * b.x; acc[1][1] += a.y * b.y;
                acc[1][2] += a.y * b.z; acc[1][3] += a.y * b.w;
                acc[2][0] += a.z * b.x; acc[2][1] += a.z * b.y;
                acc[2][2] += a.z * b.z; acc[2][3] += a.z * b.w;
                acc[3][0] += a.w * b.x; acc[3][1] += a.w * b.y;
                acc[3][2] += a.w * b.z; acc[3][3] += a.w * b.w;
            }
        }
        float4 en = *reinterpret_cast<const float4*>(&enorm[c0 + 4 * tc]);
        float enj[4] = {en.x, en.y, en.z, en.w};
#pragma unroll
        for (int i = 0; i < 4; i++)
#pragma unroll
            for (int j = 0; j < 4; j++) {
                float v = 2.0f * acc[i][j] - enj[j];
                int   c = c0 + 4 * tc + j;
                if (v > best[i]) { best[i] = v; bidx[i] = c; }
            }
    }

    __syncthreads();
#pragma unroll
    for (int i = 0; i < 4; i++) {
        redv[(4 * tr + i) * 16 + tc] = best[i];
        redi[(4 * tr + i) * 16 + tc] = bidx[i];
    }
    __syncthreads();
    if (tid < BN) {
        float bv = redv[tid * 16];
        int   bi = redi[tid * 16];
        for (int t = 1; t < 16; t++) {
            float v  = redv[tid * 16 + t];
            int   id = redi[tid * 16 + t];
            if (v > bv || (v == bv && id < bi)) { bv = v; bi = id; }
        }
        rowsel[tid] = bi;
        indout[n0 + tid] = (float)bi;
        unsafeAtomicAdd(&counts[bi], 1.0f);
    }
    __syncthreads();

    float4*   Q4   = reinterpret_cast<float4*>(quant);
    const int lane = tid & 63;
#pragma unroll
    for (int it = 0; it < 16; ++it) {
        int r   = (tid >> 6) + 4 * it;
        int idx = rowsel[r];
        float4 ev = E4[idx * 64 + lane];
        Q4[(n0 + r) * 64 + lane] = ev;
        float4 xv = X4[(n0 + r) * 64 + lane];
        float* dst = &esum[idx * D_DIM + lane * 4];
        unsafeAtomicAdd(dst + 0, xv.x);
        unsafeAtomicAdd(dst + 1, xv.y);
        unsafeAtomicAdd(dst + 2, xv.z);
        unsafeAtomicAdd(dst + 3, xv.w);
    }
}

__global__ __launch_bounds__(1024) void vq_fin1(const float* __restrict__ cs_in,
                                                const float* __restrict__ counts,
                                                float* __restrict__ cs_out,
                                                float* __restrict__ denom) {
    __shared__ float red[1024];
    int   c  = threadIdx.x;
    float cs = DECAY * cs_in[c] + OMD * counts[c];
    cs_out[c] = cs;
    red[c]    = cs;
    __syncthreads();
    for (int s = 512; s > 0; s >>= 1) {
        if (c < s) red[c] += red[c + s];
        __syncthreads();
    }
    float ntot = red[0];
    denom[c] = (cs + EPSV) / (ntot + (float)C_CODES * EPSV) * ntot;
}

__global__ __launch_bounds__(256) void vq_fin2(const float* __restrict__ ea,
                                               const float* __restrict__ esum,
                                               const float* __restrict__ denom,
                                               float* __restrict__ out) {
    int i = blockIdx.x * 256 + threadIdx.x;
    int c = i >> 6;
    float4 a = reinterpret_cast<const float4*>(ea)[i];
    float4 s = reinterpret_cast<const float4*>(esum)[i];
    float  d = denom[c];
    float4 o;
    o.x = (DECAY * a.x + OMD * s.x) / d;
    o.y = (DECAY * a.y + OMD * s.y) / d;
    o.z = (DECAY * a.z + OMD * s.z) / d;
    o.w = (DECAY * a.w + OMD * s.w) / d;
    reinterpret_cast<float4*>(out)[i] = o;
}

// ---------------------------------------------------------------------------
extern "C" void kernel_launch(void* const* d_in, const int* in_sizes, int n_in,
                              void* d_out, int out_size, void* d_ws, size_t ws_size,
                              hipStream_t stream) {
    const float* x            = (const float*)d_in[0];
    const float* embed        = (const float*)d_in[1];
    const float* embed_avg    = (const float*)d_in[2];
    const float* cluster_size = (const float*)d_in[3];

    float* out      = (float*)d_out;
    float* quant    = out;                                 // [N, D]
    float* ind      = out + (size_t)N_PTS * D_DIM;         // [N]
    float* emb_norm = ind + N_PTS;                         // [C, D]
    float* cs_out   = emb_norm + (size_t)C_CODES * D_DIM;  // [C]

    float* ws    = (float*)d_ws;
    float* enorm = ws + WS_ENORM;

    if (ws_size >= WS_TOTAL_FLOATS * sizeof(float)) {
        int*      fcnt  = (int*)(ws + WS_FCNT);
        int*      pcnt  = (int*)(ws + WS_PCNT);
        float*    xnorm = ws + WS_XNORM;
        float4*   cand4 = (float4*)(ws + WS_CAND4);
        int*      flagr = (int*)(ws + WS_FLAGR);
        unsigned long long* key64 = (unsigned long long*)(ws + WS_KEY64);
        float*    P     = ws + WS_PBUF;
        _Float16* B16   = (_Float16*)(ws + WS_B16);

        vq_prep<<<8448, 256, 0, stream>>>(x, embed, B16, enorm, xnorm, fcnt);
        vq_gemm1<<<1024, 256, 0, stream>>>(x, B16, enorm, cand4);
        vq_merge3f<<<N_PTS / 64, 256, 0, stream>>>(cand4, embed, enorm, xnorm,
                                                   quant, ind, flagr, fcnt, key64);
        vq_gemm2<<<2048, 256, 0, stream>>>(x, B16, enorm, flagr, fcnt, key64);
        vq_patch<<<N_PTS / 64, 256, 0, stream>>>(key64, flagr, fcnt, embed, quant, ind);
        vq_part<<<dim3(C_CODES / PK, PG), 256, 0, stream>>>(x, ind, P, pcnt);
        vq_comb<<<C_CODES, 256, 0, stream>>>(P, pcnt, embed_avg, cluster_size,
                                             emb_norm, cs_out);
    } else {
        // fallback: R1-proven fp32 VALU path (~550 us)
        vq_enorm<<<C_CODES / 4, 256, 0, stream>>>(embed, enorm);
        float* countsf = ws + WS_CAND4;                 // [1024]
        float* esum    = ws + WS_CAND4 + 1024;          // [1024*256]
        float* denom   = ws + WS_PBUF;                  // [1024]
        hipMemsetAsync(countsf, 0, (1024 + (size_t)C_CODES * D_DIM) * sizeof(float), stream);
        vq_main_fb<<<N_PTS / 64, 256, 0, stream>>>(x, embed, enorm, quant, ind, countsf, esum);
        vq_fin1<<<1, 1024, 0, stream>>>(cluster_size, countsf, cs_out, denom);
        vq_fin2<<<(C_CODES * D_DIM / 4) / 256, 256, 0, stream>>>(embed_avg, esum, denom, emb_norm);
    }
}

// Round 12
// 191.820 us; speedup vs baseline: 1.0597x; 1.0597x over previous
//
#include <hip/hip_runtime.h>
#include <cstdint>

#define DECAY 0.99f
#define OMD   0.01f
#define EPSV  1e-5f

constexpr int N_PTS   = 32768;  // B*T
constexpr int D_DIM   = 256;
constexpr int C_CODES = 1024;
constexpr int NKT     = 12;     // rescore K-tiles (3 segment-products x 4)
constexpr int AP      = 512;    // A row pitch: [xh | xl]  (R6-proven layout)
constexpr int BP      = 512;    // B row pitch: [eh | el]

constexpr int PG = 16;          // ind chunks (R10-proven)
constexpr int PK = 8;           // codes per partial block
constexpr int LCAP = 2048;      // worst-case list = chunk size, exact bound

typedef _Float16 half8  __attribute__((ext_vector_type(8)));
typedef _Float16 half4v __attribute__((ext_vector_type(4)));
typedef float    floatx4 __attribute__((ext_vector_type(4)));

// workspace layout (float offsets)
constexpr size_t WS_ENORM = 0;                        // float[1024]
constexpr size_t WS_FCNT  = 1024;                     // int[1]
constexpr size_t WS_XNORM = 2048;                     // float[32768] -> ends 34816
constexpr size_t WS_PCNT  = 34816;                    // int[16*1024] -> ends 51200
constexpr size_t WS_CAND4 = 51200;                    // float4[32768*8] = 1048576 floats
constexpr size_t WS_FLAGR = WS_CAND4 + 1048576;       // int[32768]
constexpr size_t WS_KEY64 = WS_FLAGR + 32768;         // u64[32768] = 65536 floats (8B aligned)
constexpr size_t WS_A16   = WS_KEY64 + 65536;         // half[32768*512] = 8388608 floats
constexpr size_t WS_B16   = WS_A16 + 8388608;         // half[1024*512]  = 262144 floats
constexpr size_t WS_TOTAL_FLOATS = WS_B16 + 262144;   // ~39.4 MB
// P[16][1024][256] = 4194304 floats aliases WS_A16 (A16 dead after vq_gemm2).

__device__ __forceinline__ void async_copy16(const void* g, void* s) {
    __builtin_amdgcn_global_load_lds(
        (const __attribute__((address_space(1))) unsigned int*)(uintptr_t)g,
        (__attribute__((address_space(3))) unsigned int*)(uintptr_t)s, 16, 0, 0);
}

// ordered-uint transform: unsigned compare of u() == float compare
__device__ __forceinline__ unsigned ord_u32(float v) {
    unsigned s = __float_as_uint(v);
    unsigned m = (unsigned)((int)s >> 31);
    return s ^ (m | 0x80000000u);
}
__device__ __forceinline__ float ord_dec(unsigned t) {
    unsigned s = (t & 0x80000000u) ? (t ^ 0x80000000u) : ~t;
    return __uint_as_float(s);
}

// fp16 low-part split, identical ops to the proven prep path
__device__ __forceinline__ _Float16 lo_h(float f) {
    _Float16 h = (_Float16)f;
    return (_Float16)(f - (float)h);
}

// ---------------------------------------------------------------------------
// FUSED prep: blocks [0,8192) split x into [xh|xl] fp16 rows (pitch 512) and
// wave-reduce xnorm[n]; blocks [8192,8448) split e into [eh|el] + enorm.
__global__ __launch_bounds__(256) void vq_prep(const float* __restrict__ X,
                                               const float* __restrict__ E,
                                               _Float16* __restrict__ A,
                                               _Float16* __restrict__ B,
                                               float* __restrict__ enorm,
                                               float* __restrict__ xnorm,
                                               int* __restrict__ fcnt) {
    if (blockIdx.x < 8192) {
        int i = blockIdx.x * 256 + threadIdx.x;      // float4 index, N*D/4 total
        int n = i >> 6, kq = (i & 63) * 4;
        float4 v = reinterpret_cast<const float4*>(X)[i];
        _Float16 h0 = (_Float16)v.x, h1 = (_Float16)v.y, h2 = (_Float16)v.z, h3 = (_Float16)v.w;
        _Float16 l0 = lo_h(v.x), l1 = lo_h(v.y), l2 = lo_h(v.z), l3 = lo_h(v.w);
        half4v hi = {h0, h1, h2, h3};
        half4v lo = {l0, l1, l2, l3};
        _Float16* row = A + (size_t)n * AP;
        *reinterpret_cast<half4v*>(row + kq)       = hi;
        *reinterpret_cast<half4v*>(row + 256 + kq) = lo;
        float s = v.x * v.x + v.y * v.y + v.z * v.z + v.w * v.w;
        int lane = threadIdx.x & 63;
#pragma unroll
        for (int off = 32; off > 0; off >>= 1) s += __shfl_down(s, off, 64);
        if (lane == 0) xnorm[n] = s;
    } else {
        if (blockIdx.x == 8192 && threadIdx.x == 0) *fcnt = 0;
        int i = (blockIdx.x - 8192) * 256 + threadIdx.x;  // float4 index, C*D/4
        int c = i >> 6, kq = (i & 63) * 4;
        float4 v = reinterpret_cast<const float4*>(E)[i];
        _Float16 h0 = (_Float16)v.x, h1 = (_Float16)v.y, h2 = (_Float16)v.z, h3 = (_Float16)v.w;
        _Float16 l0 = lo_h(v.x), l1 = lo_h(v.y), l2 = lo_h(v.z), l3 = lo_h(v.w);
        half4v hi = {h0, h1, h2, h3};
        half4v lo = {l0, l1, l2, l3};
        _Float16* row = B + (size_t)c * BP;
        *reinterpret_cast<half4v*>(row + kq)       = hi;
        *reinterpret_cast<half4v*>(row + 256 + kq) = lo;
        float s = v.x * v.x + v.y * v.y + v.z * v.z + v.w * v.w;
        int lane = threadIdx.x & 63;
#pragma unroll
        for (int off = 32; off > 0; off >>= 1) s += __shfl_down(s, off, 64);
        if (lane == 0) enorm[c] = s;
    }
}

// enorm standalone (fallback path only)
__global__ __launch_bounds__(256) void vq_enorm(const float* __restrict__ E,
                                                float* __restrict__ enorm) {
    int c    = blockIdx.x * 4 + (threadIdx.x >> 6);
    int lane = threadIdx.x & 63;
    float4 v = reinterpret_cast<const float4*>(E)[c * 64 + lane];
    float s  = v.x * v.x + v.y * v.y + v.z * v.z + v.w * v.w;
#pragma unroll
    for (int off = 32; off > 0; off >>= 1) s += __shfl_down(s, off, 64);
    if (lane == 0) enorm[c] = s;
}

// ---------------------------------------------------------------------------
// Pass-1 MFMA GEMM: xh*eh only (K=256), 128 rows x 256 codes per block,
// packed-key top-2 with DPP butterfly epilogue (R6-proven). 0 LDS ops in
// the reduce; key quantization absorbed by merge3f's inflated threshold.
#define TOP2_DPP(CTRL)                                                          \
    {                                                                           \
        unsigned o1 = (unsigned)__builtin_amdgcn_update_dpp((int)k1, (int)k1,   \
                                                            CTRL, 0xF, 0xF, false); \
        unsigned o2 = (unsigned)__builtin_amdgcn_update_dpp((int)k2, (int)k2,   \
                                                            CTRL, 0xF, 0xF, false); \
        unsigned tmn = o1 < k1 ? o1 : k1;                                       \
        k1 = o1 > k1 ? o1 : k1;                                                 \
        k2 = o2 > k2 ? o2 : k2;                                                 \
        k2 = tmn > k2 ? tmn : k2;                                               \
    }

__global__ __launch_bounds__(256, 2) void vq_gemm1(
    const _Float16* __restrict__ A, const _Float16* __restrict__ B,
    const float* __restrict__ enorm, float4* __restrict__ cand4) {
    __shared__ _Float16 As[128 * 64];   // 16 KB [row][k], chunks XOR-swizzled by row&7
    __shared__ _Float16 Bs[256 * 64];   // 32 KB

    const int L  = blockIdx.x;              // 0..1023
    const int ct = (L >> 3) & 3;            // code tile 0..3 (256 codes each)
    const int rt = (L & 7) | ((L >> 5) << 3);   // row tile; same rt -> same XCD
    const int n0  = rt * 128;
    const int cb0 = ct * 256;

    const int tid = threadIdx.x;
    const int w   = tid >> 6;
    const int l   = tid & 63;

    const int srow = l >> 3;
    const int sq   = (l & 7) ^ srow;

    floatx4 acc[4][8] = {};

    for (int kt = 0; kt < 4; ++kt) {        // K=256: hi segments only
        const int k0 = kt * 64;
        __syncthreads();
#pragma unroll
        for (int t = 0; t < 4; ++t) {       // A: 128 rows
            int rr = w * 32 + t * 8;
            const _Float16* ga = A + (size_t)(n0 + rr + srow) * AP + k0 + sq * 8;
            async_copy16(ga, &As[rr * 64]);
        }
#pragma unroll
        for (int t = 0; t < 8; ++t) {       // B: 256 rows
            int rr = w * 64 + t * 8;
            const _Float16* gb = B + (size_t)(cb0 + rr + srow) * BP + k0 + sq * 8;
            async_copy16(gb, &Bs[rr * 64]);
        }
        __syncthreads();
#pragma unroll
        for (int kk = 0; kk < 2; ++kk) {
            half8 af[4], bf[8];
            int qa = kk * 4 + (l >> 4);
#pragma unroll
            for (int i = 0; i < 4; ++i) {
                int row = (w & 1) * 64 + 16 * i + (l & 15);
                af[i] = *reinterpret_cast<const half8*>(&As[row * 64 + (qa ^ (row & 7)) * 8]);
            }
#pragma unroll
            for (int j = 0; j < 8; ++j) {
                int crow = (w >> 1) * 128 + 16 * j + (l & 15);
                bf[j] = *reinterpret_cast<const half8*>(&Bs[crow * 64 + (qa ^ (crow & 7)) * 8]);
            }
#pragma unroll
            for (int i = 0; i < 4; ++i)
#pragma unroll
                for (int j = 0; j < 8; ++j)
                    acc[i][j] = __builtin_amdgcn_mfma_f32_16x16x32_f16(af[i], bf[j], acc[i][j], 0, 0, 0);
        }
    }

    const int colbase = cb0 + (w >> 1) * 128 + (l & 15);
    float    en[8];
    unsigned idxenc[8];
#pragma unroll
    for (int j = 0; j < 8; ++j) {
        en[j]     = enorm[colbase + 16 * j];
        idxenc[j] = 1023u - (unsigned)(colbase + 16 * j);
    }

#pragma unroll
    for (int i = 0; i < 4; ++i) {
#pragma unroll
        for (int reg = 0; reg < 4; ++reg) {
            unsigned k1 = 0u, k2 = 0u;
#pragma unroll
            for (int j = 0; j < 8; ++j) {
                float v = 2.0f * acc[i][j][reg] - en[j];
                unsigned key = (ord_u32(v) & 0xFFFFFC00u) | idxenc[j];
                unsigned tmn = key < k1 ? key : k1;
                k1 = key > k1 ? key : k1;
                k2 = tmn > k2 ? tmn : k2;
            }
            TOP2_DPP(0xB1)   // quad_perm xor1
            TOP2_DPP(0x4E)   // quad_perm xor2
            TOP2_DPP(0x141)  // row_half_mirror
            TOP2_DPP(0x140)  // row_mirror
            if ((l & 15) == 0) {
                unsigned c1 = 1023u - (k1 & 1023u);
                float v1 = ord_dec(k1 & 0xFFFFFC00u);
                float v2 = ord_dec(k2 & 0xFFFFFC00u);
                int row = n0 + (w & 1) * 64 + 16 * i + (l >> 4) * 4 + reg;
                cand4[(size_t)row * 8 + ct * 2 + (w >> 1)] =
                    make_float4(v1, (float)c1, v2, 0.0f);
            }
        }
    }
}

// ---------------------------------------------------------------------------
// Merge top-2 candidates (8/row) -> provisional argmax; flag+compact
// uncertain rows (zero-init their key64 slot); gather quantize.
__global__ __launch_bounds__(256) void vq_merge3f(
    const float4* __restrict__ cand4, const float* __restrict__ E,
    const float* __restrict__ enorm, const float* __restrict__ xnorm,
    float* __restrict__ quant, float* __restrict__ indout,
    int* __restrict__ flagrows, int* __restrict__ fcnt,
    unsigned long long* __restrict__ keyarr) {
    __shared__ int   rowsel[64];
    __shared__ float emred[256];
    const int tid = threadIdx.x;
    const int n0  = blockIdx.x * 64;

    float em = fmaxf(fmaxf(enorm[tid], enorm[tid + 256]),
                     fmaxf(enorm[tid + 512], enorm[tid + 768]));
    emred[tid] = em;
    __syncthreads();
    for (int st = 128; st > 0; st >>= 1) {
        if (tid < st) emred[tid] = fmaxf(emred[tid], emred[tid + st]);
        __syncthreads();
    }
    const float emax = emred[0];

    if (tid < 64) {
        int r = n0 + tid;
        float b1 = -3.4e38f, b2 = -3.4e38f;
        int   i1 = 0x7fffffff;
#pragma unroll
        for (int t = 0; t < 8; ++t) {
            float4 cv = cand4[(size_t)r * 8 + t];
            int ci = (int)cv.y;
            if (cv.x > b1 || (cv.x == b1 && ci < i1)) { b2 = fmaxf(b1, cv.z); b1 = cv.x; i1 = ci; }
            else b2 = fmaxf(b2, cv.x);
        }
        i1 &= (C_CODES - 1);
        rowsel[tid] = i1;
        indout[r]   = (float)i1;
        float T = 0.004150390625f * sqrtf(xnorm[r] * emax)
                + 0.0001220703125f * emax + 0.5f;
        if (b1 - b2 <= T) {
            int p = atomicAdd(fcnt, 1);
            flagrows[p] = r;
            keyarr[p]   = 0ull;            // init for gemm2's atomicMax
        }
    }
    __syncthreads();

    const float4* E4 = reinterpret_cast<const float4*>(E);
    float4*       Q4 = reinterpret_cast<float4*>(quant);
    const int lane = tid & 63;
#pragma unroll
    for (int it = 0; it < 16; ++it) {
        int r   = (tid >> 6) + 4 * it;
        int idx = rowsel[r];
        Q4[(n0 + r) * 64 + lane] = E4[idx * 64 + lane];
    }
}

// ---------------------------------------------------------------------------
// Sparse rescore GEMM: full 3-split (xh*eh + xh*el + xl*eh, K=768 effective)
// over DENSE flagged slots x 1024 codes; A16 packed [xh|xl] -> pure
// global_load_lds staging (R6-proven offsets, bit-identical dists).
// Winner per slot via exact u64 atomicMax key (R9-proven).  NO fences.
__global__ __launch_bounds__(256, 2) void vq_gemm2(
    const _Float16* __restrict__ A, const _Float16* __restrict__ B,
    const float* __restrict__ enorm, const int* __restrict__ flagrows,
    const int* __restrict__ fcnt, unsigned long long* __restrict__ keyarr) {
    const int fc = *fcnt;

    const int L      = blockIdx.x;          // 0..2047 (covers worst case)
    const int within = L >> 3;
    const int ct     = within & 7;
    const int rt     = (L & 7) | ((within >> 3) << 3);
    const int n0     = rt * 128;            // dense slot base
    if (n0 >= fc) return;
    const int cb0    = ct * 128;

    __shared__ _Float16 As[128 * 64];
    __shared__ _Float16 Bs[128 * 64];

    const int tid = threadIdx.x;
    const int w   = tid >> 6;
    const int l   = tid & 63;
    const int srow = l >> 3;
    const int sq   = (l & 7) ^ srow;

    int grow[4];
#pragma unroll
    for (int t = 0; t < 4; ++t) {
        int slot = n0 + w * 32 + t * 8 + srow;
        int r    = (slot < fc) ? flagrows[slot] : 0;
        grow[t]  = r & (N_PTS - 1);
    }

    floatx4 acc[4][4] = {};

    for (int kt = 0; kt < NKT; ++kt) {
        // kt 0-3: xh*eh, 4-7: xh*el, 8-11: xl*eh  (packed pitch-512 offsets)
        const int ka = ((kt < 8) ? (kt & 3) : (kt - 4)) * 64;
        const int kb = (kt < 4) ? kt * 64 : (kt < 8 ? 256 + (kt - 4) * 64 : (kt - 8) * 64);
        __syncthreads();
#pragma unroll
        for (int t = 0; t < 4; ++t) {
            int rr = w * 32 + t * 8;
            const _Float16* ga = A + (size_t)grow[t] * AP + ka + sq * 8;
            async_copy16(ga, &As[rr * 64]);
            const _Float16* gb = B + (size_t)(cb0 + rr + srow) * BP + kb + sq * 8;
            async_copy16(gb, &Bs[rr * 64]);
        }
        __syncthreads();
#pragma unroll
        for (int kk = 0; kk < 2; ++kk) {
            half8 af[4], bf[4];
            int qa = kk * 4 + (l >> 4);
#pragma unroll
            for (int i = 0; i < 4; ++i) {
                int row  = (w & 1) * 64 + 16 * i + (l & 15);
                af[i] = *reinterpret_cast<const half8*>(&As[row * 64 + (qa ^ (row & 7)) * 8]);
                int crow = (w >> 1) * 64 + 16 * i + (l & 15);
                bf[i] = *reinterpret_cast<const half8*>(&Bs[crow * 64 + (qa ^ (crow & 7)) * 8]);
            }
#pragma unroll
            for (int i = 0; i < 4; ++i)
#pragma unroll
                for (int j = 0; j < 4; ++j)
                    acc[i][j] = __builtin_amdgcn_mfma_f32_16x16x32_f16(af[i], bf[j], acc[i][j], 0, 0, 0);
        }
    }

    const int colbase = cb0 + (w >> 1) * 64 + (l & 15);
    float en[4];
#pragma unroll
    for (int j = 0; j < 4; ++j) en[j] = enorm[colbase + 16 * j];

#pragma unroll
    for (int i = 0; i < 4; ++i) {
#pragma unroll
        for (int reg = 0; reg < 4; ++reg) {
            float bv = -3.4e38f;
            int   bi = 0x7fffffff;
#pragma unroll
            for (int j = 0; j < 4; ++j) {
                float v = 2.0f * acc[i][j][reg] - en[j];
                int   c = colbase + 16 * j;
                if (v > bv || (v == bv && c < bi)) { bv = v; bi = c; }
            }
#pragma unroll
            for (int s = 1; s < 16; s <<= 1) {
                float ov = __shfl_xor(bv, s, 64);
                int   oi = __shfl_xor(bi, s, 64);
                if (ov > bv || (ov == bv && oi < bi)) { bv = ov; bi = oi; }
            }
            if ((l & 15) == 0) {
                int slot = n0 + (w & 1) * 64 + 16 * i + (l >> 4) * 4 + reg;
                unsigned long long key =
                    ((unsigned long long)ord_u32(bv) << 10) | (1023u - (unsigned)bi);
                atomicMax(&keyarr[slot], key);
            }
        }
    }
}

// ---------------------------------------------------------------------------
// Patch: decode per-slot winner key; overwrite ind + quantize rows.
__global__ __launch_bounds__(256) void vq_patch(
    const unsigned long long* __restrict__ keyarr, const int* __restrict__ flagrows,
    const int* __restrict__ fcnt, const float* __restrict__ E,
    float* __restrict__ quant, float* __restrict__ indout) {
    int fc = *fcnt;
    if (fc > N_PTS) fc = N_PTS;
    const int s0 = blockIdx.x * 64;
    if (s0 >= fc) return;

    __shared__ int rowsel[64];
    __shared__ int rowid[64];
    const int tid = threadIdx.x;
    if (tid < 64) {
        int s = s0 + tid;
        if (s < fc) {
            unsigned long long k = keyarr[s];
            int c = (int)(1023u - (unsigned)(k & 1023u)) & (C_CODES - 1);
            int r = flagrows[s] & (N_PTS - 1);
            rowsel[tid] = c;
            rowid[tid]  = r;
            indout[r]   = (float)c;
        } else {
            rowsel[tid] = -1;
            rowid[tid]  = 0;
        }
    }
    __syncthreads();

    const float4* E4 = reinterpret_cast<const float4*>(E);
    float4*       Q4 = reinterpret_cast<float4*>(quant);
    const int lane = tid & 63;
#pragma unroll
    for (int it = 0; it < 16; ++it) {
        int rs  = (tid >> 6) + 4 * it;
        int idx = rowsel[rs];
        if (idx >= 0) Q4[(size_t)rowid[rs] * 64 + lane] = E4[idx * 64 + lane];
    }
}

// ---------------------------------------------------------------------------
// Partial esum: block (cg, g) scans ind chunk g (2048 entries) for its PK=8
// codes, gathers matching X rows with 8-deep ILP, writes P[g][code][d] +
// counts.  (R10-proven, PG=16.)
__global__ __launch_bounds__(256) void vq_part(
    const float* __restrict__ X, const float* __restrict__ indf,
    float* __restrict__ P, int* __restrict__ pcnt) {
    __shared__ int list[LCAP];
    __shared__ int cnt[PK];
    __shared__ int lcnt;
    const int cg = blockIdx.x;   // 0..127 code group
    const int g  = blockIdx.y;   // 0..15 ind chunk
    const int t  = threadIdx.x;
    if (t == 0) lcnt = 0;
    if (t < PK) cnt[t] = 0;
    __syncthreads();

    const float4* I4 = reinterpret_cast<const float4*>(indf);
    float4 v[2];
#pragma unroll
    for (int j = 0; j < 2; ++j)            // 2 independent loads, one latency round
        v[j] = I4[g * 512 + j * 256 + t];

#pragma unroll
    for (int j = 0; j < 2; ++j) {
        int base = (g * 512 + j * 256 + t) * 4;
        int k0 = (int)v[j].x, k1 = (int)v[j].y, k2 = (int)v[j].z, k3 = (int)v[j].w;
        if ((k0 >> 3) == cg) { int p = atomicAdd(&lcnt, 1); atomicAdd(&cnt[k0 & 7], 1); if (p < LCAP) list[p] = ((base + 0) << 3) | (k0 & 7); }
        if ((k1 >> 3) == cg) { int p = atomicAdd(&lcnt, 1); atomicAdd(&cnt[k1 & 7], 1); if (p < LCAP) list[p] = ((base + 1) << 3) | (k1 & 7); }
        if ((k2 >> 3) == cg) { int p = atomicAdd(&lcnt, 1); atomicAdd(&cnt[k2 & 7], 1); if (p < LCAP) list[p] = ((base + 2) << 3) | (k2 & 7); }
        if ((k3 >> 3) == cg) { int p = atomicAdd(&lcnt, 1); atomicAdd(&cnt[k3 & 7], 1); if (p < LCAP) list[p] = ((base + 3) << 3) | (k3 & 7); }
    }
    __syncthreads();

    int m = lcnt; if (m > LCAP) m = LCAP;
    float acc[PK] = {0, 0, 0, 0, 0, 0, 0, 0};
    int r = 0;
    for (; r + 8 <= m; r += 8) {           // 8 coalesced row loads in flight
        int e[8];
        float val[8];
#pragma unroll
        for (int q = 0; q < 8; ++q) e[q] = list[r + q];
#pragma unroll
        for (int q = 0; q < 8; ++q) val[q] = X[(size_t)(e[q] >> 3) * D_DIM + t];
#pragma unroll
        for (int q = 0; q < 8; ++q) {
            int k = e[q] & 7;
#pragma unroll
            for (int kk = 0; kk < PK; ++kk) acc[kk] += (k == kk) ? val[q] : 0.0f;
        }
    }
    for (; r < m; ++r) {
        int e = list[r];
        float val = X[(size_t)(e >> 3) * D_DIM + t];
        int k = e & 7;
#pragma unroll
        for (int kk = 0; kk < PK; ++kk) acc[kk] += (k == kk) ? val : 0.0f;
    }

#pragma unroll
    for (int kk = 0; kk < PK; ++kk)
        P[((size_t)g * C_CODES + cg * PK + kk) * D_DIM + t] = acc[kk];
    if (t < PK) pcnt[g * C_CODES + cg * PK + t] = cnt[t];
}

// ---------------------------------------------------------------------------
// Combine partials + fused EMA/laplace epilogue + FUSED cs_sum reduction.
__global__ __launch_bounds__(256) void vq_comb(
    const float* __restrict__ P, const int* __restrict__ pcnt,
    const float* __restrict__ ea, const float* __restrict__ cs_in,
    float* __restrict__ emb_norm, float* __restrict__ cs_out) {
    __shared__ float red[256];
    const int c = blockIdx.x;
    const int t = threadIdx.x;
    red[t] = cs_in[t] + cs_in[t + 256] + cs_in[t + 512] + cs_in[t + 768];
    __syncthreads();
    for (int st = 128; st > 0; st >>= 1) {
        if (t < st) red[t] += red[t + st];
        __syncthreads();
    }
    const float cssum = red[0];

    float s = 0.0f;
#pragma unroll
    for (int g = 0; g < PG; ++g)
        s += P[((size_t)g * C_CODES + c) * D_DIM + t];
    int total = 0;
#pragma unroll
    for (int g = 0; g < PG; ++g) total += pcnt[g * C_CODES + c];
    float cs    = DECAY * cs_in[c] + OMD * (float)total;
    float ntot  = DECAY * cssum + OMD * (float)N_PTS;   // sum(cs_new) closed form
    float denom = (cs + EPSV) / (ntot + (float)C_CODES * EPSV) * ntot;
    emb_norm[(size_t)c * D_DIM + t] =
        (DECAY * ea[(size_t)c * D_DIM + t] + OMD * s) / denom;
    if (t == 0) cs_out[c] = cs;
}

// ---------------------------------------------------------------------------
// FALLBACK (R1-proven, only if ws too small): fp32 VALU GEMM + atomic epilogue.
__global__ __launch_bounds__(256) void vq_main_fb(
    const float* __restrict__ X, const float* __restrict__ E,
    const float* __restrict__ enorm,
    float* __restrict__ quant, float* __restrict__ indout,
    float* __restrict__ counts, float* __restrict__ esum) {
    constexpr int BN = 64, BC = 64, BK = 32, PADR = 68;
    __shared__ float As[BK * PADR];
    __shared__ float Bs[BK * PADR];
    __shared__ float redv[BN * 16];
    __shared__ int   redi[BN * 16];
    __shared__ int   rowsel[BN];

    const int tid = threadIdx.x;
    const int n0  = blockIdx.x * BN;
    const int tr  = tid >> 4;
    const int tc  = tid & 15;
    const int sr  = tid >> 2;
    const int sk  = tid & 3;

    const float4* X4 = reinterpret_cast<const float4*>(X);
    const float4* E4 = reinterpret_cast<const float4*>(E);

    float best[4];
    int   bidx[4];
#pragma unroll
    for (int i = 0; i < 4; i++) { best[i] = -3.4e38f; bidx[i] = 0; }

    for (int c0 = 0; c0 < C_CODES; c0 += BC) {
        float acc[4][4] = {};
        for (int k0 = 0; k0 < D_DIM; k0 += BK) {
            __syncthreads();
#pragma unroll
            for (int it = 0; it < 2; ++it) {
                int   k4 = sk + 4 * it;
                float4 av = X4[(n0 + sr) * 64 + (k0 >> 2) + k4];
                float4 bv = E4[(c0 + sr) * 64 + (k0 >> 2) + k4];
                int kk = k4 * 4;
                As[(kk + 0) * PADR + sr] = av.x;
                As[(kk + 1) * PADR + sr] = av.y;
                As[(kk + 2) * PADR + sr] = av.z;
                As[(kk + 3) * PADR + sr] = av.w;
                Bs[(kk + 0) * PADR + sr] = bv.x;
                Bs[(kk + 1) * PADR + sr] = bv.y;
                Bs[(kk + 2) * PADR + sr] = bv.z;
                Bs[(kk + 3) * PADR + sr] = bv.w;
            }
            __syncthreads();
#pragma unroll
            for (int k = 0; k < BK; ++k) {
                float4 a = *reinterpret_cast<const float4*>(&As[k * PADR + 4 * tr]);
                float4 b = *reinterpret_cast<const float4*>(&Bs[k * PADR + 4 * tc]);
                acc[0][0] += a.x * b.x; acc[0][1] += a.x * b.y;
                acc[0][2] += a.x * b.z; acc[0][3] += a.x * b.w;
                acc[1][0] += a.y * b.x; acc[1][1] += a.y * b.y;
                acc[1][2] += a.y * b.z; acc[1][3] += a.y * b.w;
                acc[2][0] += a.z * b.x; acc[2][1] += a.z * b.y;
                acc[2][2] += a.z * b.z; acc[2][3] += a.z * b.w;
                acc[3][0] += a.w * b.x; acc[3][1] += a.w * b.y;
                acc[3][2] += a.w * b.z; acc[3][3] += a.w * b.w;
            }
        }
        float4 en = *reinterpret_cast<const float4*>(&enorm[c0 + 4 * tc]);
        float enj[4] = {en.x, en.y, en.z, en.w};
#pragma unroll
        for (int i = 0; i < 4; i++)
#pragma unroll
            for (int j = 0; j < 4; j++) {
                float v = 2.0f * acc[i][j] - enj[j];
                int   c = c0 + 4 * tc + j;
                if (v > best[i]) { best[i] = v; bidx[i] = c; }
            }
    }

    __syncthreads();
#pragma unroll
    for (int i = 0; i < 4; i++) {
        redv[(4 * tr + i) * 16 + tc] = best[i];
        redi[(4 * tr + i) * 16 + tc] = bidx[i];
    }
    __syncthreads();
    if (tid < BN) {
        float bv = redv[tid * 16];
        int   bi = redi[tid * 16];
        for (int t = 1; t < 16; t++) {
            float v  = redv[tid * 16 + t];
            int   id = redi[tid * 16 + t];
            if (v > bv || (v == bv && id < bi)) { bv = v; bi = id; }
        }
        rowsel[tid] = bi;
        indout[n0 + tid] = (float)bi;
        unsafeAtomicAdd(&counts[bi], 1.0f);
    }
    __syncthreads();

    float4*   Q4   = reinterpret_cast<float4*>(quant);
    const int lane = tid & 63;
#pragma unroll
    for (int it = 0; it < 16; ++it) {
        int r   = (tid >> 6) + 4 * it;
        int idx = rowsel[r];
        float4 ev = E4[idx * 64 + lane];
        Q4[(n0 + r) * 64 + lane] = ev;
        float4 xv = X4[(n0 + r) * 64 + lane];
        float* dst = &esum[idx * D_DIM + lane * 4];
        unsafeAtomicAdd(dst + 0, xv.x);
        unsafeAtomicAdd(dst + 1, xv.y);
        unsafeAtomicAdd(dst + 2, xv.z);
        unsafeAtomicAdd(dst + 3, xv.w);
    }
}

__global__ __launch_bounds__(1024) void vq_fin1(const float* __restrict__ cs_in,
                                                const float* __restrict__ counts,
                                                float* __restrict__ cs_out,
                                                float* __restrict__ denom) {
    __shared__ float red[1024];
    int   c  = threadIdx.x;
    float cs = DECAY * cs_in[c] + OMD * counts[c];
    cs_out[c] = cs;
    red[c]    = cs;
    __syncthreads();
    for (int s = 512; s > 0; s >>= 1) {
        if (c < s) red[c] += red[c + s];
        __syncthreads();
    }
    float ntot = red[0];
    denom[c] = (cs + EPSV) / (ntot + (float)C_CODES * EPSV) * ntot;
}

__global__ __launch_bounds__(256) void vq_fin2(const float* __restrict__ ea,
                                               const float* __restrict__ esum,
                                               const float* __restrict__ denom,
                                               float* __restrict__ out) {
    int i = blockIdx.x * 256 + threadIdx.x;
    int c = i >> 6;
    float4 a = reinterpret_cast<const float4*>(ea)[i];
    float4 s = reinterpret_cast<const float4*>(esum)[i];
    float  d = denom[c];
    float4 o;
    o.x = (DECAY * a.x + OMD * s.x) / d;
    o.y = (DECAY * a.y + OMD * s.y) / d;
    o.z = (DECAY * a.z + OMD * s.z) / d;
    o.w = (DECAY * a.w + OMD * s.w) / d;
    reinterpret_cast<float4*>(out)[i] = o;
}

// ---------------------------------------------------------------------------
extern "C" void kernel_launch(void* const* d_in, const int* in_sizes, int n_in,
                              void* d_out, int out_size, void* d_ws, size_t ws_size,
                              hipStream_t stream) {
    const float* x            = (const float*)d_in[0];
    const float* embed        = (const float*)d_in[1];
    const float* embed_avg    = (const float*)d_in[2];
    const float* cluster_size = (const float*)d_in[3];

    float* out      = (float*)d_out;
    float* quant    = out;                                 // [N, D]
    float* ind      = out + (size_t)N_PTS * D_DIM;         // [N]
    float* emb_norm = ind + N_PTS;                         // [C, D]
    float* cs_out   = emb_norm + (size_t)C_CODES * D_DIM;  // [C]

    float* ws    = (float*)d_ws;
    float* enorm = ws + WS_ENORM;

    if (ws_size >= WS_TOTAL_FLOATS * sizeof(float)) {
        int*      fcnt  = (int*)(ws + WS_FCNT);
        int*      pcnt  = (int*)(ws + WS_PCNT);
        float*    xnorm = ws + WS_XNORM;
        float4*   cand4 = (float4*)(ws + WS_CAND4);
        int*      flagr = (int*)(ws + WS_FLAGR);
        unsigned long long* key64 = (unsigned long long*)(ws + WS_KEY64);
        _Float16* A16   = (_Float16*)(ws + WS_A16);
        _Float16* B16   = (_Float16*)(ws + WS_B16);
        float*    P     = ws + WS_A16;                  // aliases A16 (dead after vq_gemm2)

        vq_prep<<<8448, 256, 0, stream>>>(x, embed, A16, B16, enorm, xnorm, fcnt);
        vq_gemm1<<<1024, 256, 0, stream>>>(A16, B16, enorm, cand4);
        vq_merge3f<<<N_PTS / 64, 256, 0, stream>>>(cand4, embed, enorm, xnorm,
                                                   quant, ind, flagr, fcnt, key64);
        vq_gemm2<<<2048, 256, 0, stream>>>(A16, B16, enorm, flagr, fcnt, key64);
        vq_patch<<<N_PTS / 64, 256, 0, stream>>>(key64, flagr, fcnt, embed, quant, ind);
        vq_part<<<dim3(C_CODES / PK, PG), 256, 0, stream>>>(x, ind, P, pcnt);
        vq_comb<<<C_CODES, 256, 0, stream>>>(P, pcnt, embed_avg, cluster_size,
                                             emb_norm, cs_out);
    } else {
        // fallback: R1-proven fp32 VALU path (~550 us)
        vq_enorm<<<C_CODES / 4, 256, 0, stream>>>(embed, enorm);
        float* countsf = ws + WS_CAND4;                 // [1024]
        float* esum    = ws + WS_CAND4 + 1024;          // [1024*256]
        float* denom   = ws + WS_A16;                   // [1024]
        hipMemsetAsync(countsf, 0, (1024 + (size_t)C_CODES * D_DIM) * sizeof(float), stream);
        vq_main_fb<<<N_PTS / 64, 256, 0, stream>>>(x, embed, enorm, quant, ind, countsf, esum);
        vq_fin1<<<1, 1024, 0, stream>>>(cluster_size, countsf, cs_out, denom);
        vq_fin2<<<(C_CODES * D_DIM / 4) / 256, 256, 0, stream>>>(embed_avg, esum, denom, emb_norm);
    }
}